// Round 1
// baseline (1751.509 us; speedup 1.0000x reference)
//
#include <hip/hip_runtime.h>
#include <hip/hip_bf16.h>
#include <float.h>

#define B_ 4
#define N_ 1024
#define DIM_ 1024
#define H_ 16
#define DH_ 64
#define NM_ 4
#define J_ 1028          // N_ + NM_
#define TOPK_ 64
#define QKSCALE 10.0f

typedef __attribute__((ext_vector_type(8))) short short8;
typedef __attribute__((ext_vector_type(4))) float f32x4;
typedef __attribute__((ext_vector_type(8))) unsigned short ushort8;
typedef __attribute__((ext_vector_type(4))) unsigned short ushort4v;

__device__ __forceinline__ float b2f(unsigned short u){
  union { unsigned int i; float f; } c; c.i = ((unsigned int)u) << 16; return c.f;
}
__device__ __forceinline__ unsigned short f2b(float f){
  union { float f; unsigned int i; } c; c.f = f;
  unsigned int r = c.i + 0x7FFFu + ((c.i >> 16) & 1u);   // RNE
  return (unsigned short)(r >> 16);
}

// ---------------- f32 -> bf16 convert (grid-stride) ----------------
__global__ void k_cvt(const float* __restrict__ s, unsigned short* __restrict__ d, int n){
  int i = blockIdx.x * 256 + threadIdx.x;
  int st = gridDim.x * 256;
  for (; i < n; i += st) d[i] = f2b(s[i]);
}

// ---------------- memory-slot prep: normalize mem_k, copy mem_v ----------------
__global__ __launch_bounds__(256) void k_mem(const float* __restrict__ mk, const float* __restrict__ mv,
                                             unsigned short* __restrict__ kn, unsigned short* __restrict__ vc){
  int wid = blockIdx.x * 4 + (threadIdx.x >> 6);   // 0..63
  int lane = threadIdx.x & 63;
  int h = wid >> 2, mm = wid & 3;
  float kv = mk[(h * NM_ + mm) * DH_ + lane];
  float ss = kv * kv;
  #pragma unroll
  for (int off = 32; off; off >>= 1) ss += __shfl_xor(ss, off);
  float rn = 1.f / fmaxf(sqrtf(ss), 1e-12f);
  unsigned short kb = f2b(kv * rn);
  unsigned short vb = f2b(mv[(h * NM_ + mm) * DH_ + lane]);
  for (int b = 0; b < B_; ++b){
    int base = ((b * H_ + h) * J_ + mm) * DH_ + lane;
    kn[base] = kb;
    vc[base] = vb;
  }
}

// ---------------- bf16 MFMA GEMM 4096x1024x1024, 128x128 tile, 4 waves ----------------
// MODE 0: v  -> vc  [b,h,4+i,d] bf16
// MODE 1: q  -> qn  [b,h,i,d]   bf16, l2norm * QKSCALE
// MODE 2: k  -> kn  [b,h,4+i,d] bf16, l2norm
// MODE 3: gate -> sigmoid(P + bg) bf16 [m,col]
// MODE 4: f32 out [m,col]
template<int MODE>
__global__ __launch_bounds__(256) void k_gemm(const unsigned short* __restrict__ A,
                                              const unsigned short* __restrict__ W,
                                              void* __restrict__ outp,
                                              const float* __restrict__ bg)
{
  __shared__ unsigned short As[128][40];   // [m][k], +8 pad
  __shared__ unsigned short Bs[128][40];   // [n][k] (transposed), +8 pad
  const int t = threadIdx.x;
  const int m0 = blockIdx.y * 128, n0 = blockIdx.x * 128;
  const int l = t & 63, w = t >> 6, wr = w >> 1, wc = w & 1;

  f32x4 acc[4][4];
  #pragma unroll
  for (int a = 0; a < 4; ++a)
    #pragma unroll
    for (int b2 = 0; b2 < 4; ++b2) acc[a][b2] = (f32x4){0.f, 0.f, 0.f, 0.f};

  for (int k0 = 0; k0 < 1024; k0 += 32){
    #pragma unroll
    for (int cc = 0; cc < 2; ++cc){          // A tile: 128x32
      int c = t + cc * 256;
      int row = c >> 2, colc = (c & 3) * 8;
      *(ushort8*)&As[row][colc] = *(const ushort8*)&A[(m0 + row) * 1024 + k0 + colc];
    }
    #pragma unroll
    for (int cc = 0; cc < 2; ++cc){          // B tile: 32x128, store transposed
      int c = t + cc * 256;
      int kk = c >> 4, nc = (c & 15) * 8;
      ushort8 vb = *(const ushort8*)&W[(k0 + kk) * 1024 + n0 + nc];
      #pragma unroll
      for (int e = 0; e < 8; ++e) Bs[nc + e][kk] = vb[e];
    }
    __syncthreads();
    short8 af[4], bfr[4];
    #pragma unroll
    for (int mf = 0; mf < 4; ++mf) af[mf]  = *(const short8*)&As[wr * 64 + mf * 16 + (l & 15)][(l >> 4) * 8];
    #pragma unroll
    for (int nf = 0; nf < 4; ++nf) bfr[nf] = *(const short8*)&Bs[wc * 64 + nf * 16 + (l & 15)][(l >> 4) * 8];
    #pragma unroll
    for (int mf = 0; mf < 4; ++mf)
      #pragma unroll
      for (int nf = 0; nf < 4; ++nf)
        acc[mf][nf] = __builtin_amdgcn_mfma_f32_16x16x32_bf16(af[mf], bfr[nf], acc[mf][nf], 0, 0, 0);
    __syncthreads();
  }

  // epilogue; C/D frag: row = (l>>4)*4 + r, col = l&15 (guide-verified)
  int hcol = (n0 + wc * 64) >> 6;     // head for this wave's 64-col span
  #pragma unroll
  for (int mf = 0; mf < 4; ++mf){
    #pragma unroll
    for (int r = 0; r < 4; ++r){
      int row = m0 + wr * 64 + mf * 16 + (l >> 4) * 4 + r;
      float rn = 1.f;
      if (MODE == 1 || MODE == 2){
        float ss = 0.f;
        #pragma unroll
        for (int nf = 0; nf < 4; ++nf) ss += acc[mf][nf][r] * acc[mf][nf][r];
        #pragma unroll
        for (int off = 1; off < 16; off <<= 1) ss += __shfl_xor(ss, off);  // over the head's 64 cols
        rn = 1.f / fmaxf(sqrtf(ss), 1e-12f);
        if (MODE == 1) rn *= QKSCALE;
      }
      #pragma unroll
      for (int nf = 0; nf < 4; ++nf){
        int col = n0 + wc * 64 + nf * 16 + (l & 15);
        float v = acc[mf][nf][r];
        if (MODE == 4){
          ((float*)outp)[row * 1024 + col] = v;
        } else if (MODE == 3){
          float g = v + bg[col];
          ((unsigned short*)outp)[row * 1024 + col] = f2b(1.f / (1.f + __expf(-g)));
        } else {
          int bb = row >> 10, ii = row & 1023;
          int d = nf * 16 + (l & 15);
          if (MODE == 1)
            ((unsigned short*)outp)[((bb * H_ + hcol) * N_ + ii) * DH_ + d] = f2b(v * rn);
          else
            ((unsigned short*)outp)[((bb * H_ + hcol) * J_ + NM_ + ii) * DH_ + d] = f2b(v * rn);
        }
      }
    }
  }
}

// ---------------- fused attention: one workgroup per (b, i) ----------------
__global__ __launch_bounds__(256) void k_attn(
  const unsigned short* __restrict__ qn, const unsigned short* __restrict__ kn,
  const unsigned short* __restrict__ vc, const float* __restrict__ wpre,
  const float* __restrict__ wpost, const float* __restrict__ hsc,
  const unsigned short* __restrict__ gate, unsigned short* __restrict__ aout)
{
  __shared__ float sd[16][J_];     // mixed dots -> attn (in place)
  __shared__ float sq[16][64];     // q rows for this i (pre-scaled by QKSCALE)
  __shared__ float spre[256];
  __shared__ float spost[256];

  const int blk = blockIdx.x;
  const int b = blk >> 10, i = blk & 1023;
  const int t = threadIdx.x;
  const int nA = i + 5;            // allowed cols: j < i+5 (4 memory slots + causal)

  spre[t]  = wpre[t];
  spost[t] = wpost[t];
  #pragma unroll
  for (int p = 0; p < 4; ++p){
    int h = p * 4 + (t >> 6), d = t & 63;
    sq[h][d] = b2f(qn[((b * H_ + h) * N_ + i) * DH_ + d]);
  }
  __syncthreads();

  // ---- raw dots (all 16 heads) + W_pre mix, one column j per thread ----
  for (int j = t; j < J_; j += 256){
    if (j < nA){
      float mixed[16];
      #pragma unroll
      for (int h = 0; h < 16; ++h) mixed[h] = 0.f;
      for (int g = 0; g < 16; ++g){
        const ushort8* kp = (const ushort8*)(kn + ((b * H_ + g) * J_ + j) * DH_);
        float a = 0.f;
        #pragma unroll
        for (int c = 0; c < 8; ++c){
          ushort8 kv = kp[c];
          #pragma unroll
          for (int e = 0; e < 8; ++e) a += sq[g][c * 8 + e] * b2f(kv[e]);
        }
        #pragma unroll
        for (int h = 0; h < 16; ++h) mixed[h] += spre[h * 16 + g] * a;
      }
      #pragma unroll
      for (int h = 0; h < 16; ++h) sd[h][j] = mixed[h];
    } else {
      #pragma unroll
      for (int h = 0; h < 16; ++h) sd[h][j] = 0.f;
    }
  }
  __syncthreads();

  // ---- per-head top-64 threshold + softmax (one wave per head-row) ----
  const int w = t >> 6, lane = t & 63;
  for (int h = w; h < 16; h += 4){
    float v[17]; unsigned int key[17];
    #pragma unroll
    for (int r = 0; r < 17; ++r){
      int j = lane + 64 * r;
      float x = (j < nA) ? sd[h][j] : -FLT_MAX;
      v[r] = x;
      unsigned int u = __float_as_uint(x);
      key[r] = (u >> 31) ? ~u : (u | 0x80000000u);   // monotone order-preserving map
    }
    float mx = v[0];
    #pragma unroll
    for (int r = 1; r < 17; ++r) mx = fmaxf(mx, v[r]);
    #pragma unroll
    for (int off = 32; off; off >>= 1) mx = fmaxf(mx, __shfl_xor(mx, off));

    unsigned int T = 0u;
    if (nA > TOPK_){
      for (int bit = 31; bit >= 8; --bit){     // 24-bit greedy search for 64th-largest key
        unsigned int Tc = T | (1u << bit);
        int c = 0;
        #pragma unroll
        for (int r = 0; r < 17; ++r) c += (key[r] >= Tc) ? 1 : 0;
        #pragma unroll
        for (int off = 32; off; off >>= 1) c += __shfl_xor(c, off);
        if (c >= TOPK_) T = Tc;
      }
    }
    float s = 0.f;
    #pragma unroll
    for (int r = 0; r < 17; ++r){
      int j = lane + 64 * r;
      float e = (j < nA && key[r] >= T) ? __expf(v[r] - mx) : 0.f;
      v[r] = e; s += e;
    }
    #pragma unroll
    for (int off = 32; off; off >>= 1) s += __shfl_xor(s, off);
    float inv = 1.f / s;
    #pragma unroll
    for (int r = 0; r < 17; ++r){
      int j = lane + 64 * r;
      if (j < J_) sd[h][j] = v[r] * inv;
    }
  }
  __syncthreads();

  // ---- W_post mix (in place, whole column per thread: no cross-thread hazard) ----
  for (int j = t; j < nA; j += 256){
    float a[16];
    #pragma unroll
    for (int g = 0; g < 16; ++g) a[g] = sd[g][j];
    #pragma unroll
    for (int h = 0; h < 16; ++h){
      float m = 0.f;
      #pragma unroll
      for (int g = 0; g < 16; ++g) m += spost[h * 16 + g] * a[g];
      sd[h][j] = m;
    }
  }
  __syncthreads();

  // ---- PV + head_scale + gate: thread (h, sg) does 4 d's ----
  const int h = t >> 4, sg = t & 15, d0 = sg * 4;
  const unsigned short* vbase = vc + ((b * H_ + h) * J_) * DH_ + d0;
  float acc[4] = {0.f, 0.f, 0.f, 0.f};
  for (int j = 0; j < nA; ++j){
    float a = sd[h][j];
    ushort4v vv = *(const ushort4v*)(vbase + j * DH_);
    acc[0] += a * b2f(vv[0]);
    acc[1] += a * b2f(vv[1]);
    acc[2] += a * b2f(vv[2]);
    acc[3] += a * b2f(vv[3]);
  }
  float hs = hsc[h];
  #pragma unroll
  for (int r = 0; r < 4; ++r){
    float g = b2f(gate[blk * 1024 + h * 64 + d0 + r]);
    aout[blk * 1024 + h * 64 + d0 + r] = f2b(acc[r] * hs * g);
  }
}

// ---------------- host ----------------
extern "C" void kernel_launch(void* const* d_in, const int* in_sizes, int n_in,
                              void* d_out, int out_size, void* d_ws, size_t ws_size,
                              hipStream_t stream) {
  const float* x     = (const float*)d_in[0];
  const float* Wq    = (const float*)d_in[1];
  const float* Wk    = (const float*)d_in[2];
  const float* Wv    = (const float*)d_in[3];
  const float* Wpre  = (const float*)d_in[4];
  const float* Wpost = (const float*)d_in[5];
  const float* mk    = (const float*)d_in[6];
  const float* mv    = (const float*)d_in[7];
  const float* hsc   = (const float*)d_in[8];
  const float* Wg    = (const float*)d_in[9];
  const float* bg    = (const float*)d_in[10];
  const float* Wo    = (const float*)d_in[11];
  float* out = (float*)d_out;

  char* ws = (char*)d_ws;
  size_t off = 0;
  auto alloc = [&](size_t bytes) -> void* {
    void* p = ws + off; off += (bytes + 255) & ~(size_t)255; return p;
  };
  unsigned short* xb   = (unsigned short*)alloc((size_t)4096 * 1024 * 2);
  unsigned short* wqb  = (unsigned short*)alloc((size_t)1024 * 1024 * 2);
  unsigned short* wkb  = (unsigned short*)alloc((size_t)1024 * 1024 * 2);
  unsigned short* wvb  = (unsigned short*)alloc((size_t)1024 * 1024 * 2);
  unsigned short* wgb  = (unsigned short*)alloc((size_t)1024 * 1024 * 2);
  unsigned short* wob  = (unsigned short*)alloc((size_t)1024 * 1024 * 2);
  unsigned short* qn   = (unsigned short*)alloc((size_t)B_ * H_ * N_ * DH_ * 2);
  unsigned short* kn   = (unsigned short*)alloc((size_t)B_ * H_ * J_ * DH_ * 2);
  unsigned short* vc   = (unsigned short*)alloc((size_t)B_ * H_ * J_ * DH_ * 2);
  unsigned short* gate = (unsigned short*)alloc((size_t)4096 * 1024 * 2);
  unsigned short* aout = (unsigned short*)alloc((size_t)4096 * 1024 * 2);

  k_cvt<<<1024, 256, 0, stream>>>(x,  xb,  4096 * 1024);
  k_cvt<<<512,  256, 0, stream>>>(Wq, wqb, 1024 * 1024);
  k_cvt<<<512,  256, 0, stream>>>(Wk, wkb, 1024 * 1024);
  k_cvt<<<512,  256, 0, stream>>>(Wv, wvb, 1024 * 1024);
  k_cvt<<<512,  256, 0, stream>>>(Wg, wgb, 1024 * 1024);
  k_cvt<<<512,  256, 0, stream>>>(Wo, wob, 1024 * 1024);

  k_mem<<<16, 256, 0, stream>>>(mk, mv, kn, vc);

  dim3 gg(8, 32);
  k_gemm<0><<<gg, 256, 0, stream>>>(xb, wvb, vc,   nullptr);
  k_gemm<1><<<gg, 256, 0, stream>>>(xb, wqb, qn,   nullptr);
  k_gemm<2><<<gg, 256, 0, stream>>>(xb, wkb, kn,   nullptr);
  k_gemm<3><<<gg, 256, 0, stream>>>(xb, wgb, gate, bg);

  k_attn<<<4096, 256, 0, stream>>>(qn, kn, vc, Wpre, Wpost, hsc, gate, aout);

  k_gemm<4><<<gg, 256, 0, stream>>>(aout, wob, out, nullptr);
}